// Round 1
// baseline (144.882 us; speedup 1.0000x reference)
//
#include <hip/hip_runtime.h>

// Problem constants: frames [B, T, C, H, W] = [8, 8, 3, 256, 256] fp32
#define BB 8
#define TT 8
#define CC 3
#define HH 256
#define WW 256
#define PAIRS (BB * (TT - 1))       // 56
#define TX 32
#define TY 8
#define TILES_X (WW / TX)           // 8
#define TILES_Y (HH / TY)           // 32
#define NBLOCKS (PAIRS * TILES_X * TILES_Y)  // 14336
#define FRAME_PIX (HH * WW)         // 65536
#define EPS 1e-3f

// loss = sum_{b,t,y,x} (|u_p-u_g| + |v_p-v_g|) * mm / (PAIRS*2*H*W)
#define INV_N (1.0f / (float)((size_t)PAIRS * 2 * HH * WW))

__global__ __launch_bounds__(TX * TY) void flow_loss_kernel(
    const float* __restrict__ pred, const float* __restrict__ gt,
    float* __restrict__ partial)
{
    // LDS: grayscale of frame t with 1-px halo, for pred and gt.
    // Row stride 34 floats -> lanes tx..tx+2 spread over banks; 2-way aliasing
    // max for wave64 on 32 banks (free per G4).
    __shared__ float sp[TY + 2][TX + 2];
    __shared__ float sg[TY + 2][TX + 2];

    const int pair = blockIdx.z;          // 0..55
    const int b = pair / (TT - 1);
    const int t = pair % (TT - 1);

    const size_t frame_stride = (size_t)CC * FRAME_PIX;
    const float* p1 = pred + ((size_t)b * TT + t) * frame_stride;
    const float* p2 = p1 + frame_stride;
    const float* g1 = gt + ((size_t)b * TT + t) * frame_stride;
    const float* g2 = g1 + frame_stride;

    const int x0 = blockIdx.x * TX - 1;
    const int y0 = blockIdx.y * TY - 1;
    const int tid = threadIdx.y * TX + threadIdx.x;

    // Cooperative halo load: (TX+2)*(TY+2)=340 gray values from 3 channels each.
    for (int i = tid; i < (TX + 2) * (TY + 2); i += TX * TY) {
        const int lx = i % (TX + 2);
        const int ly = i / (TX + 2);
        const int gx = x0 + lx;
        const int gy = y0 + ly;
        float vp = 0.0f, vg = 0.0f;
        if ((unsigned)gx < WW && (unsigned)gy < HH) {  // zero pad outside
            const int idx = gy * WW + gx;
            vp = 0.2989f * p1[idx] + 0.587f * p1[idx + FRAME_PIX]
               + 0.114f * p1[idx + 2 * FRAME_PIX];
            vg = 0.2989f * g1[idx] + 0.587f * g1[idx + FRAME_PIX]
               + 0.114f * g1[idx + 2 * FRAME_PIX];
        }
        sp[ly][lx] = vp;
        sg[ly][lx] = vg;
    }
    __syncthreads();

    const int gx = blockIdx.x * TX + threadIdx.x;
    const int gy = blockIdx.y * TY + threadIdx.y;
    const int idx = gy * WW + gx;

    // Center loads: frame t+1 channels (pred & gt) and gt frame t channels
    // (for motion magnitude). gt t+1 channels shared with its gray.
    const float p2r = p2[idx], p2g = p2[idx + FRAME_PIX], p2b = p2[idx + 2 * FRAME_PIX];
    const float g2r = g2[idx], g2g = g2[idx + FRAME_PIX], g2b = g2[idx + 2 * FRAME_PIX];
    const float g1r = g1[idx], g1g = g1[idx + FRAME_PIX], g1b = g1[idx + 2 * FRAME_PIX];

    const float gray_p2 = 0.2989f * p2r + 0.587f * p2g + 0.114f * p2b;
    const float gray_g2 = 0.2989f * g2r + 0.587f * g2g + 0.114f * g2b;
    const float mm = (fabsf(g2r - g1r) + fabsf(g2g - g1g) + fabsf(g2b - g1b)) * (1.0f / 3.0f);

    const int lx = threadIdx.x + 1;
    const int ly = threadIdx.y + 1;

    // --- pred flow ---
    float a00 = sp[ly - 1][lx - 1], a01 = sp[ly - 1][lx], a02 = sp[ly - 1][lx + 1];
    float a10 = sp[ly    ][lx - 1], a11 = sp[ly    ][lx], a12 = sp[ly    ][lx + 1];
    float a20 = sp[ly + 1][lx - 1], a21 = sp[ly + 1][lx], a22 = sp[ly + 1][lx + 1];
    float Ix = (a00 - a02) + 2.0f * (a10 - a12) + (a20 - a22);
    float Iy = (a00 + 2.0f * a01 + a02) - (a20 + 2.0f * a21 + a22);
    float It = gray_p2 - a11;
    float d  = Ix * Ix + Iy * Iy + EPS;
    float up = -(Ix * It) / d;
    float vp = -(Iy * It) / d;

    // --- gt flow ---
    a00 = sg[ly - 1][lx - 1]; a01 = sg[ly - 1][lx]; a02 = sg[ly - 1][lx + 1];
    a10 = sg[ly    ][lx - 1]; a11 = sg[ly    ][lx]; a12 = sg[ly    ][lx + 1];
    a20 = sg[ly + 1][lx - 1]; a21 = sg[ly + 1][lx]; a22 = sg[ly + 1][lx + 1];
    Ix = (a00 - a02) + 2.0f * (a10 - a12) + (a20 - a22);
    Iy = (a00 + 2.0f * a01 + a02) - (a20 + 2.0f * a21 + a22);
    It = gray_g2 - a11;
    d  = Ix * Ix + Iy * Iy + EPS;
    const float ug = -(Ix * It) / d;
    const float vg = -(Iy * It) / d;

    float s = (fabsf(up - ug) + fabsf(vp - vg)) * mm;

    // Block reduction: wave64 shuffle, then 4 wave sums via LDS.
    #pragma unroll
    for (int off = 32; off > 0; off >>= 1) s += __shfl_down(s, off, 64);

    __shared__ float wsum[TX * TY / 64];
    if ((tid & 63) == 0) wsum[tid >> 6] = s;
    __syncthreads();
    if (tid == 0) {
        float bs = 0.0f;
        #pragma unroll
        for (int w = 0; w < TX * TY / 64; ++w) bs += wsum[w];
        partial[(blockIdx.z * TILES_Y + blockIdx.y) * TILES_X + blockIdx.x] = bs;
    }
}

__global__ __launch_bounds__(256) void reduce_kernel(
    const float* __restrict__ partial, float* __restrict__ out)
{
    float s = 0.0f;
    for (int i = threadIdx.x; i < NBLOCKS; i += 256) s += partial[i];
    #pragma unroll
    for (int off = 32; off > 0; off >>= 1) s += __shfl_down(s, off, 64);

    __shared__ float wsum[4];
    if ((threadIdx.x & 63) == 0) wsum[threadIdx.x >> 6] = s;
    __syncthreads();
    if (threadIdx.x == 0) {
        out[0] = (wsum[0] + wsum[1] + wsum[2] + wsum[3]) * INV_N;
    }
}

extern "C" void kernel_launch(void* const* d_in, const int* in_sizes, int n_in,
                              void* d_out, int out_size, void* d_ws, size_t ws_size,
                              hipStream_t stream) {
    const float* pred = (const float*)d_in[0];
    const float* gt   = (const float*)d_in[1];
    float* partial    = (float*)d_ws;   // NBLOCKS floats = 57344 B
    float* out        = (float*)d_out;

    dim3 grid(TILES_X, TILES_Y, PAIRS);
    dim3 block(TX, TY);
    flow_loss_kernel<<<grid, block, 0, stream>>>(pred, gt, partial);
    reduce_kernel<<<1, 256, 0, stream>>>(partial, out);
}

// Round 2
// 128.437 us; speedup vs baseline: 1.1280x; 1.1280x over previous
//
#include <hip/hip_runtime.h>

// Frames [B, T, C, H, W] = [8, 8, 3, 256, 256] fp32
#define BB 8
#define TT 8
#define HH 256
#define WW 256
#define PAIRS (BB * (TT - 1))        // 56
#define FRAME_PIX (HH * WW)          // 65536
#define RROWS 8                      // tile rows per block
#define HROWS (RROWS + 2)            // 10 (with halo)
#define PADW 264                     // 4 zero-pad floats each side of 256
#define NY (HH / RROWS)              // 32 y-tiles
#define NBLK (PAIRS * NY)            // 1792 blocks
#define EPS 1e-3f
#define INV_N (1.0f / (float)((size_t)PAIRS * 2 * HH * WW))

__device__ __forceinline__ float4 ld4(const float* __restrict__ p) {
    return *reinterpret_cast<const float4*>(p);
}

// Tile: full image row width (256) x 8 rows. 256 threads, 4 px per thread
// per pass, 2 passes. Grayscale of frame t (pred & gt) staged in LDS with
// 1-row halo and 4-float zero side pads (zero padding = conv 'SAME').
__global__ __launch_bounds__(256) void flow_loss_kernel(
    const float* __restrict__ pred, const float* __restrict__ gt,
    float* __restrict__ partial)
{
    __shared__ float sg[2][HROWS][PADW];   // 21120 B

    const int ytile = blockIdx.x;
    const int pair  = blockIdx.y;
    const int b = pair / (TT - 1);
    const int t = pair % (TT - 1);
    const size_t fs = (size_t)3 * FRAME_PIX;
    const float* p1 = pred + ((size_t)b * TT + t) * fs;
    const float* p2 = p1 + fs;
    const float* g1 = gt + ((size_t)b * TT + t) * fs;
    const float* g2 = g1 + fs;

    const int y0 = ytile * RROWS;
    const int tid = threadIdx.x;

    // ---- Stage grayscale of frame t (both images) into padded LDS ----
    // 66 float4 slots per row: slot 0 and 65 are zero pads (cols -4..-1, 256..259).
    for (int i = tid; i < 2 * HROWS * 66; i += 256) {
        const int img = i / (HROWS * 66);
        const int rem = i - img * (HROWS * 66);
        const int row = rem / 66;
        const int p   = rem - row * 66;
        const int yr  = y0 - 1 + row;
        float vx = 0.f, vy = 0.f, vz = 0.f, vw = 0.f;
        if (p >= 1 && p <= 64 && (unsigned)yr < HH) {
            const float* base = img ? g1 : p1;
            const int off = yr * WW + (p - 1) * 4;
            const float4 r  = ld4(base + off);
            const float4 g  = ld4(base + off + FRAME_PIX);
            const float4 bl = ld4(base + off + 2 * FRAME_PIX);
            vx = 0.2989f * r.x + 0.587f * g.x + 0.114f * bl.x;
            vy = 0.2989f * r.y + 0.587f * g.y + 0.114f * bl.y;
            vz = 0.2989f * r.z + 0.587f * g.z + 0.114f * bl.z;
            vw = 0.2989f * r.w + 0.587f * g.w + 0.114f * bl.w;
        }
        float4 v; v.x = vx; v.y = vy; v.z = vz; v.w = vw;
        *reinterpret_cast<float4*>(&sg[img][row][p * 4]) = v;
    }
    __syncthreads();

    // ---- Compute: thread -> 4 px (x = (tid&63)*4), row = tid>>6 + 4*pass ----
    const int c4 = tid & 63;
    const int rb = tid >> 6;
    const int x  = c4 * 4;
    float s = 0.f;

    #pragma unroll
    for (int pass = 0; pass < 2; ++pass) {
        const int r   = pass * 4 + rb;      // tile row 0..7
        const int y   = y0 + r;
        const int idx = y * WW + x;

        // Center loads: g1 (motion mag), g2, p2 channels (float4 each).
        const float4 ar = ld4(g1 + idx), ag = ld4(g1 + idx + FRAME_PIX), ab = ld4(g1 + idx + 2 * FRAME_PIX);
        const float4 br = ld4(g2 + idx), bg = ld4(g2 + idx + FRAME_PIX), bb = ld4(g2 + idx + 2 * FRAME_PIX);
        const float4 cr = ld4(p2 + idx), cg = ld4(p2 + idx + FRAME_PIX), cb = ld4(p2 + idx + 2 * FRAME_PIX);

        float gp2[4], gg2[4], mm[4];
        gp2[0] = 0.2989f * cr.x + 0.587f * cg.x + 0.114f * cb.x;
        gp2[1] = 0.2989f * cr.y + 0.587f * cg.y + 0.114f * cb.y;
        gp2[2] = 0.2989f * cr.z + 0.587f * cg.z + 0.114f * cb.z;
        gp2[3] = 0.2989f * cr.w + 0.587f * cg.w + 0.114f * cb.w;
        gg2[0] = 0.2989f * br.x + 0.587f * bg.x + 0.114f * bb.x;
        gg2[1] = 0.2989f * br.y + 0.587f * bg.y + 0.114f * bb.y;
        gg2[2] = 0.2989f * br.z + 0.587f * bg.z + 0.114f * bb.z;
        gg2[3] = 0.2989f * br.w + 0.587f * bg.w + 0.114f * bb.w;
        mm[0] = (fabsf(br.x - ar.x) + fabsf(bg.x - ag.x) + fabsf(bb.x - ab.x)) * (1.0f / 3.0f);
        mm[1] = (fabsf(br.y - ar.y) + fabsf(bg.y - ag.y) + fabsf(bb.y - ab.y)) * (1.0f / 3.0f);
        mm[2] = (fabsf(br.z - ar.z) + fabsf(bg.z - ag.z) + fabsf(bb.z - ab.z)) * (1.0f / 3.0f);
        mm[3] = (fabsf(br.w - ar.w) + fabsf(bg.w - ag.w) + fabsf(bb.w - ab.w)) * (1.0f / 3.0f);

        float up[4], vp[4];
        #pragma unroll
        for (int img = 0; img < 2; ++img) {
            // Window: padded col index of image col x is x+4; need cols x-1..x+4
            // = padded floats [x+3 .. x+8] -> three aligned float4s at x, x+4, x+8.
            float w0[6], w1[6], w2[6];
            {
                const float* b0 = &sg[img][r][x];
                const float4 A = ld4(b0), B = ld4(b0 + 4), C = ld4(b0 + 8);
                w0[0] = A.w; w0[1] = B.x; w0[2] = B.y; w0[3] = B.z; w0[4] = B.w; w0[5] = C.x;
            }
            {
                const float* b1 = &sg[img][r + 1][x];
                const float4 A = ld4(b1), B = ld4(b1 + 4), C = ld4(b1 + 8);
                w1[0] = A.w; w1[1] = B.x; w1[2] = B.y; w1[3] = B.z; w1[4] = B.w; w1[5] = C.x;
            }
            {
                const float* b2 = &sg[img][r + 2][x];
                const float4 A = ld4(b2), B = ld4(b2 + 4), C = ld4(b2 + 8);
                w2[0] = A.w; w2[1] = B.x; w2[2] = B.y; w2[3] = B.z; w2[4] = B.w; w2[5] = C.x;
            }
            #pragma unroll
            for (int j = 0; j < 4; ++j) {
                const float Ix = (w0[j] - w0[j + 2]) + 2.0f * (w1[j] - w1[j + 2]) + (w2[j] - w2[j + 2]);
                const float Iy = (w0[j] + 2.0f * w0[j + 1] + w0[j + 2])
                               - (w2[j] + 2.0f * w2[j + 1] + w2[j + 2]);
                const float It = (img ? gg2[j] : gp2[j]) - w1[j + 1];
                const float d  = Ix * Ix + Iy * Iy + EPS;
                const float inv = 1.0f / d;
                if (img == 0) {
                    up[j] = -(Ix * It) * inv;
                    vp[j] = -(Iy * It) * inv;
                } else {
                    s += (fabsf(up[j] + (Ix * It) * inv) + fabsf(vp[j] + (Iy * It) * inv)) * mm[j];
                }
            }
        }
    }

    // ---- Block reduction -> one partial per block ----
    #pragma unroll
    for (int off = 32; off > 0; off >>= 1) s += __shfl_down(s, off, 64);

    __shared__ float wsum[4];
    if ((tid & 63) == 0) wsum[tid >> 6] = s;
    __syncthreads();
    if (tid == 0) {
        partial[pair * NY + ytile] = wsum[0] + wsum[1] + wsum[2] + wsum[3];
    }
}

__global__ __launch_bounds__(256) void reduce_kernel(
    const float* __restrict__ partial, float* __restrict__ out)
{
    float s = 0.0f;
    for (int i = threadIdx.x; i < NBLK / 4; i += 256) {   // 448 float4s
        const float4 v = ld4(partial + 4 * i);
        s += (v.x + v.y) + (v.z + v.w);
    }
    #pragma unroll
    for (int off = 32; off > 0; off >>= 1) s += __shfl_down(s, off, 64);

    __shared__ float wsum[4];
    if ((threadIdx.x & 63) == 0) wsum[threadIdx.x >> 6] = s;
    __syncthreads();
    if (threadIdx.x == 0) {
        out[0] = (wsum[0] + wsum[1] + wsum[2] + wsum[3]) * INV_N;
    }
}

extern "C" void kernel_launch(void* const* d_in, const int* in_sizes, int n_in,
                              void* d_out, int out_size, void* d_ws, size_t ws_size,
                              hipStream_t stream) {
    const float* pred = (const float*)d_in[0];
    const float* gt   = (const float*)d_in[1];
    float* partial    = (float*)d_ws;     // NBLK floats = 7168 B
    float* out        = (float*)d_out;

    dim3 grid(NY, PAIRS);                 // (32, 56) = 1792 blocks
    dim3 block(256);
    flow_loss_kernel<<<grid, block, 0, stream>>>(pred, gt, partial);
    reduce_kernel<<<1, 256, 0, stream>>>(partial, out);
}

// Round 3
// 122.064 us; speedup vs baseline: 1.1869x; 1.0522x over previous
//
#include <hip/hip_runtime.h>

// Frames [B, T, C, H, W] = [8, 8, 3, 256, 256] fp32
#define BB 8
#define TT 8
#define HH 256
#define WW 256
#define FRAME_PIX (HH * WW)
#define RROWS 8                      // strip rows per block
#define PADW 264                     // 4 zero-pad floats each side of 256
#define NY (HH / RROWS)              // 32
#define NBLK (BB * 2 * NY)           // 512 blocks
#define EPS 1e-3f
#define INV_N (1.0f / (float)((size_t)BB * (TT - 1) * 2 * HH * WW))

__device__ __forceinline__ float4 ld4(const float* __restrict__ p) {
    return *reinterpret_cast<const float4*>(p);
}

__device__ __forceinline__ float4 gray4(const float4 r, const float4 g, const float4 b) {
    float4 o;
    o.x = 0.2989f * r.x + 0.587f * g.x + 0.114f * b.x;
    o.y = 0.2989f * r.y + 0.587f * g.y + 0.114f * b.y;
    o.z = 0.2989f * r.z + 0.587f * g.z + 0.114f * b.z;
    o.w = 0.2989f * r.w + 0.587f * g.w + 0.114f * b.w;
    return o;
}

// Block owns an 8-row strip of one batch element over a run of frames
// (half 0: pairs t=0..3, frames 0..4; half 1: pairs t=4..6, frames 4..7).
// Each frame's channels are loaded from global exactly once per block:
// gray of frame t+1 center is computed in registers during pair t's compute
// phase and written into LDS after a barrier; only 2 halo rows need extra
// loads. gt channels of frame t carry in registers for motion magnitude.
__global__ __launch_bounds__(256, 2) void flow_loss_kernel(
    const float* __restrict__ pred, const float* __restrict__ gt,
    float* __restrict__ partial)
{
    __shared__ float gbuf[2][RROWS + 2][PADW];   // 42240 B; row 0 = y0-1

    const int ytile = blockIdx.x;
    const int half  = blockIdx.y;
    const int b     = blockIdx.z;
    const int t0    = half * 4;
    const int npair = half ? 3 : 4;
    const int y0    = ytile * RROWS;
    const int tid   = threadIdx.x;
    const size_t fs = (size_t)3 * FRAME_PIX;
    const float* pb = pred + (size_t)b * TT * fs;
    const float* gb = gt   + (size_t)b * TT * fs;

    // compute mapping: 2 passes x (row rb_, 4 px at col cx)
    const int cx  = (tid & 63) * 4;
    const int rb_ = tid >> 6;

    // halo mapping: 256 threads -> {img 0/1} x {top,bottom row} x 64 float4s
    const int h_img  = tid >> 7;
    const int h_rsel = (tid >> 6) & 1;
    const int h_x    = (tid & 63) * 4;
    const int h_y    = h_rsel ? (y0 + RROWS) : (y0 - 1);
    const bool h_ok  = ((unsigned)h_y) < HH;
    const int h_brow = h_rsel ? (RROWS + 1) : 0;
    const size_t h_off = h_ok ? ((size_t)h_y * WW + h_x) : 0;

    // zero the side pads (cols 0..3 and 260..263 of every row) once
    if (tid < 160) {
        const int img = tid / 80, rem = tid % 80, row = rem / 8, k = rem % 8;
        const int col = (k < 4) ? k : (k + 256);
        gbuf[img][row][col] = 0.f;
    }

    float4 g1c[2][3];   // gt channels of frame t at this thread's pixels

    // ---- Prologue: stage frame t0 gray (center via compute map, halo rows) ----
    {
        const float* p1 = pb + (size_t)t0 * fs;
        const float* g1 = gb + (size_t)t0 * fs;
        float4 pg[2], gg[2];
        #pragma unroll
        for (int pass = 0; pass < 2; ++pass) {
            const int r = pass * 4 + rb_;
            const size_t off = (size_t)(y0 + r) * WW + cx;
            const float4 pr = ld4(p1 + off), pgc = ld4(p1 + off + FRAME_PIX),
                         pbc = ld4(p1 + off + 2 * FRAME_PIX);
            g1c[pass][0] = ld4(g1 + off);
            g1c[pass][1] = ld4(g1 + off + FRAME_PIX);
            g1c[pass][2] = ld4(g1 + off + 2 * FRAME_PIX);
            pg[pass] = gray4(pr, pgc, pbc);
            gg[pass] = gray4(g1c[pass][0], g1c[pass][1], g1c[pass][2]);
        }
        const float* hb = h_img ? g1 : p1;
        float4 hg = make_float4(0.f, 0.f, 0.f, 0.f);
        if (h_ok) {
            const float4 r0 = ld4(hb + h_off), g0 = ld4(hb + h_off + FRAME_PIX),
                         b0 = ld4(hb + h_off + 2 * FRAME_PIX);
            hg = gray4(r0, g0, b0);
        }
        #pragma unroll
        for (int pass = 0; pass < 2; ++pass) {
            const int r = pass * 4 + rb_;
            *reinterpret_cast<float4*>(&gbuf[0][r + 1][cx + 4]) = pg[pass];
            *reinterpret_cast<float4*>(&gbuf[1][r + 1][cx + 4]) = gg[pass];
        }
        *reinterpret_cast<float4*>(&gbuf[h_img][h_brow][h_x + 4]) = hg;
    }
    __syncthreads();

    float s = 0.f;
    for (int t = t0; t < t0 + npair; ++t) {
        const float* p2 = pb + (size_t)(t + 1) * fs;
        const float* g2 = gb + (size_t)(t + 1) * fs;

        // Issue all frame-(t+1) loads up front (center channels + halo rows)
        float4 p2c[2][3], g2c[2][3];
        #pragma unroll
        for (int pass = 0; pass < 2; ++pass) {
            const int r = pass * 4 + rb_;
            const size_t off = (size_t)(y0 + r) * WW + cx;
            p2c[pass][0] = ld4(p2 + off);
            p2c[pass][1] = ld4(p2 + off + FRAME_PIX);
            p2c[pass][2] = ld4(p2 + off + 2 * FRAME_PIX);
            g2c[pass][0] = ld4(g2 + off);
            g2c[pass][1] = ld4(g2 + off + FRAME_PIX);
            g2c[pass][2] = ld4(g2 + off + 2 * FRAME_PIX);
        }
        const float* hb = h_img ? g2 : p2;
        float4 hgray = make_float4(0.f, 0.f, 0.f, 0.f);
        if (h_ok) {
            const float4 r0 = ld4(hb + h_off), g0 = ld4(hb + h_off + FRAME_PIX),
                         b0 = ld4(hb + h_off + 2 * FRAME_PIX);
            hgray = gray4(r0, g0, b0);
        }

        float4 gp2[2], gg2[2];
        #pragma unroll
        for (int pass = 0; pass < 2; ++pass) {
            gp2[pass] = gray4(p2c[pass][0], p2c[pass][1], p2c[pass][2]);
            gg2[pass] = gray4(g2c[pass][0], g2c[pass][1], g2c[pass][2]);
        }

        // Compute pair t: Sobel on frame t from LDS, It vs register grays
        #pragma unroll
        for (int pass = 0; pass < 2; ++pass) {
            const int r = pass * 4 + rb_;
            float mm[4];
            mm[0] = (fabsf(g2c[pass][0].x - g1c[pass][0].x) + fabsf(g2c[pass][1].x - g1c[pass][1].x)
                   + fabsf(g2c[pass][2].x - g1c[pass][2].x)) * (1.f / 3.f);
            mm[1] = (fabsf(g2c[pass][0].y - g1c[pass][0].y) + fabsf(g2c[pass][1].y - g1c[pass][1].y)
                   + fabsf(g2c[pass][2].y - g1c[pass][2].y)) * (1.f / 3.f);
            mm[2] = (fabsf(g2c[pass][0].z - g1c[pass][0].z) + fabsf(g2c[pass][1].z - g1c[pass][1].z)
                   + fabsf(g2c[pass][2].z - g1c[pass][2].z)) * (1.f / 3.f);
            mm[3] = (fabsf(g2c[pass][0].w - g1c[pass][0].w) + fabsf(g2c[pass][1].w - g1c[pass][1].w)
                   + fabsf(g2c[pass][2].w - g1c[pass][2].w)) * (1.f / 3.f);

            float up[4], vp[4];
            #pragma unroll
            for (int img = 0; img < 2; ++img) {
                // padded cols cx+3..cx+8 -> aligned float4s at cx, cx+4, cx+8
                float w0[6], w1[6], w2[6];
                {
                    const float* p = &gbuf[img][r][cx];
                    const float4 A = ld4(p), B = ld4(p + 4), C = ld4(p + 8);
                    w0[0] = A.w; w0[1] = B.x; w0[2] = B.y; w0[3] = B.z; w0[4] = B.w; w0[5] = C.x;
                }
                {
                    const float* p = &gbuf[img][r + 1][cx];
                    const float4 A = ld4(p), B = ld4(p + 4), C = ld4(p + 8);
                    w1[0] = A.w; w1[1] = B.x; w1[2] = B.y; w1[3] = B.z; w1[4] = B.w; w1[5] = C.x;
                }
                {
                    const float* p = &gbuf[img][r + 2][cx];
                    const float4 A = ld4(p), B = ld4(p + 4), C = ld4(p + 8);
                    w2[0] = A.w; w2[1] = B.x; w2[2] = B.y; w2[3] = B.z; w2[4] = B.w; w2[5] = C.x;
                }
                const float4 gr2 = img ? gg2[pass] : gp2[pass];
                const float g2a[4] = {gr2.x, gr2.y, gr2.z, gr2.w};
                #pragma unroll
                for (int j = 0; j < 4; ++j) {
                    const float Ix = (w0[j] - w0[j + 2]) + 2.0f * (w1[j] - w1[j + 2]) + (w2[j] - w2[j + 2]);
                    const float Iy = (w0[j] + 2.0f * w0[j + 1] + w0[j + 2])
                                   - (w2[j] + 2.0f * w2[j + 1] + w2[j + 2]);
                    const float It = g2a[j] - w1[j + 1];
                    const float inv = 1.0f / (Ix * Ix + Iy * Iy + EPS);
                    if (img == 0) {
                        up[j] = -(Ix * It) * inv;
                        vp[j] = -(Iy * It) * inv;
                    } else {
                        s += (fabsf(up[j] + (Ix * It) * inv) + fabsf(vp[j] + (Iy * It) * inv)) * mm[j];
                    }
                }
            }
        }
        __syncthreads();

        // Rotate: write frame t+1 gray into LDS, carry gt channels in regs
        #pragma unroll
        for (int pass = 0; pass < 2; ++pass) {
            const int r = pass * 4 + rb_;
            *reinterpret_cast<float4*>(&gbuf[0][r + 1][cx + 4]) = gp2[pass];
            *reinterpret_cast<float4*>(&gbuf[1][r + 1][cx + 4]) = gg2[pass];
            g1c[pass][0] = g2c[pass][0];
            g1c[pass][1] = g2c[pass][1];
            g1c[pass][2] = g2c[pass][2];
        }
        *reinterpret_cast<float4*>(&gbuf[h_img][h_brow][h_x + 4]) = hgray;
        __syncthreads();
    }

    // ---- Block reduction -> one partial per block ----
    #pragma unroll
    for (int off = 32; off > 0; off >>= 1) s += __shfl_down(s, off, 64);

    __shared__ float wsum[4];
    if ((tid & 63) == 0) wsum[tid >> 6] = s;
    __syncthreads();
    if (tid == 0) {
        partial[(b * 2 + half) * NY + ytile] = wsum[0] + wsum[1] + wsum[2] + wsum[3];
    }
}

__global__ __launch_bounds__(256) void reduce_kernel(
    const float* __restrict__ partial, float* __restrict__ out)
{
    float s = partial[threadIdx.x] + partial[threadIdx.x + 256];
    #pragma unroll
    for (int off = 32; off > 0; off >>= 1) s += __shfl_down(s, off, 64);

    __shared__ float wsum[4];
    if ((threadIdx.x & 63) == 0) wsum[threadIdx.x >> 6] = s;
    __syncthreads();
    if (threadIdx.x == 0) {
        out[0] = (wsum[0] + wsum[1] + wsum[2] + wsum[3]) * INV_N;
    }
}

extern "C" void kernel_launch(void* const* d_in, const int* in_sizes, int n_in,
                              void* d_out, int out_size, void* d_ws, size_t ws_size,
                              hipStream_t stream) {
    const float* pred = (const float*)d_in[0];
    const float* gt   = (const float*)d_in[1];
    float* partial    = (float*)d_ws;     // NBLK floats = 2048 B
    float* out        = (float*)d_out;

    dim3 grid(NY, 2, BB);                 // (32, 2, 8) = 512 blocks
    dim3 block(256);
    flow_loss_kernel<<<grid, block, 0, stream>>>(pred, gt, partial);
    reduce_kernel<<<1, 256, 0, stream>>>(partial, out);
}

// Round 4
// 121.025 us; speedup vs baseline: 1.1971x; 1.0086x over previous
//
#include <hip/hip_runtime.h>

// Frames [B, T, C, H, W] = [8, 8, 3, 256, 256] fp32
#define BB 8
#define TT 8
#define HH 256
#define WW 256
#define FRAME_PIX (HH * WW)
#define XW 128                       // tile width
#define RROWS 8                      // tile rows
#define NYT (HH / RROWS)             // 32
#define NXT (WW / XW)                // 2
#define PADW 136                     // 4 pad + 128 + 4 pad floats
#define NBLK (BB * 2 * NYT * NXT)    // 1024 blocks
#define EPS 1e-3f
#define INV_N (1.0f / (float)((size_t)BB * (TT - 1) * 2 * HH * WW))

__device__ __forceinline__ float4 ld4(const float* __restrict__ p) {
    return *reinterpret_cast<const float4*>(p);
}
__device__ __forceinline__ void st4(float* p, const float4 v) {
    *reinterpret_cast<float4*>(p) = v;
}
__device__ __forceinline__ float4 gray4(const float4 r, const float4 g, const float4 b) {
    float4 o;
    o.x = 0.2989f * r.x + 0.587f * g.x + 0.114f * b.x;
    o.y = 0.2989f * r.y + 0.587f * g.y + 0.114f * b.y;
    o.z = 0.2989f * r.z + 0.587f * g.z + 0.114f * b.z;
    o.w = 0.2989f * r.w + 0.587f * g.w + 0.114f * b.w;
    return o;
}

// Block = 128x8 pixel tile of one batch element, marching over a frame run
// (half 0: pairs 0..3 / frames 0..4; half 1: pairs 4..6 / frames 4..7).
// Frame channels loaded once; gray of frame t+1 computed in regs during
// pair t and rotated into LDS. One-frame-lookahead prefetch: loads for
// frame t+2 are issued before pair-t compute and first consumed after the
// rotate barrier. Motion-mag is pipelined as 4 scalars (mm for pair t+1
// computed from g2c/g2n before g2c is overwritten).
__global__ __launch_bounds__(256, 4) void flow_loss_kernel(
    const float* __restrict__ pred, const float* __restrict__ gt,
    float* __restrict__ partial)
{
    __shared__ float gbuf[2][RROWS + 2][PADW];   // 10880 B; row 0 = y0-1

    const int ytile = blockIdx.x >> 1;
    const int xtile = blockIdx.x & 1;
    const int half  = blockIdx.y;
    const int b     = blockIdx.z;
    const int t0    = half * 4;
    const int tend  = t0 + (half ? 3 : 4);
    const int y0    = ytile * RROWS;
    const int x0    = xtile * XW;
    const int tid   = threadIdx.x;
    const size_t fs = (size_t)3 * FRAME_PIX;
    const float* pb = pred + (size_t)b * TT * fs;
    const float* gb = gt   + (size_t)b * TT * fs;

    // compute mapping: single pass, row r (0..7), 4 px at col cx (0..124)
    const int r  = tid >> 5;
    const int cx = (tid & 31) * 4;
    const size_t coff = (size_t)(y0 + r) * WW + (x0 + cx);

    // "extra" staging role: tid<128 -> halo rows; 128..167 -> side pads
    bool e_act = false, e_val = false;
    int  e_img = 0;
    size_t e_off = 0;
    float* e_dst = &gbuf[0][0][0];
    if (tid < 128) {
        e_act = true;
        e_img = tid >> 6;
        const int rsel = (tid >> 5) & 1;
        const int ec   = (tid & 31) * 4;
        const int ey   = rsel ? (y0 + RROWS) : (y0 - 1);
        e_val = (unsigned)ey < HH;
        e_off = e_val ? ((size_t)ey * WW + x0 + ec) : 0;
        e_dst = &gbuf[e_img][rsel ? RROWS + 1 : 0][4 + ec];
    } else if (tid < 168) {
        const int j = tid - 128;
        e_act = true;
        e_img = j / 20;
        const int rem  = j % 20;
        const int side = rem / 10;
        const int prow = rem % 10;
        const int ey = y0 - 1 + prow;
        const int ex = side ? (x0 + XW) : (x0 - 4);
        e_val = ((unsigned)ey < HH) && ((unsigned)ex < WW);
        e_off = e_val ? ((size_t)ey * WW + ex) : 0;
        e_dst = &gbuf[e_img][prow][side ? 4 + XW : 0];
    }

    float4 p2c[3], g2c[3], ecur[3];
    float  mmc[4];

    // ---- Prologue: stage frame t0, load frame t0+1, mm for pair t0 ----
    {
        const float* p1 = pb + (size_t)t0 * fs;
        const float* g1 = gb + (size_t)t0 * fs;
        const float4 pr  = ld4(p1 + coff);
        const float4 pg  = ld4(p1 + coff + FRAME_PIX);
        const float4 pbl = ld4(p1 + coff + 2 * FRAME_PIX);
        const float4 a0  = ld4(g1 + coff);
        const float4 a1  = ld4(g1 + coff + FRAME_PIX);
        const float4 a2  = ld4(g1 + coff + 2 * FRAME_PIX);
        // extras of frame t0
        const float* eb0 = e_img ? g1 : p1;
        float4 x0v = make_float4(0.f,0.f,0.f,0.f), x1v = x0v, x2v = x0v;
        if (e_act && e_val) {
            x0v = ld4(eb0 + e_off);
            x1v = ld4(eb0 + e_off + FRAME_PIX);
            x2v = ld4(eb0 + e_off + 2 * FRAME_PIX);
        }
        // frame t0+1 (cur)
        const float* p2 = p1 + fs;
        const float* g2 = g1 + fs;
        p2c[0] = ld4(p2 + coff);
        p2c[1] = ld4(p2 + coff + FRAME_PIX);
        p2c[2] = ld4(p2 + coff + 2 * FRAME_PIX);
        g2c[0] = ld4(g2 + coff);
        g2c[1] = ld4(g2 + coff + FRAME_PIX);
        g2c[2] = ld4(g2 + coff + 2 * FRAME_PIX);
        const float* eb1 = e_img ? g2 : p2;
        ecur[0] = make_float4(0.f,0.f,0.f,0.f); ecur[1] = ecur[0]; ecur[2] = ecur[0];
        if (e_act && e_val) {
            ecur[0] = ld4(eb1 + e_off);
            ecur[1] = ld4(eb1 + e_off + FRAME_PIX);
            ecur[2] = ld4(eb1 + e_off + 2 * FRAME_PIX);
        }
        // write gray(t0) to LDS
        st4(&gbuf[0][r + 1][4 + cx], gray4(pr, pg, pbl));
        st4(&gbuf[1][r + 1][4 + cx], gray4(a0, a1, a2));
        if (e_act) st4(e_dst, gray4(x0v, x1v, x2v));
        // motion mag for pair t0
        mmc[0] = (fabsf(g2c[0].x - a0.x) + fabsf(g2c[1].x - a1.x) + fabsf(g2c[2].x - a2.x)) * (1.f/3.f);
        mmc[1] = (fabsf(g2c[0].y - a0.y) + fabsf(g2c[1].y - a1.y) + fabsf(g2c[2].y - a2.y)) * (1.f/3.f);
        mmc[2] = (fabsf(g2c[0].z - a0.z) + fabsf(g2c[1].z - a1.z) + fabsf(g2c[2].z - a2.z)) * (1.f/3.f);
        mmc[3] = (fabsf(g2c[0].w - a0.w) + fabsf(g2c[1].w - a1.w) + fabsf(g2c[2].w - a2.w)) * (1.f/3.f);
    }
    __syncthreads();

    float s = 0.f;
    for (int t = t0; t < tend; ++t) {
        const bool more = (t + 1 < tend);

        // Prefetch frame t+2 (consumed after the rotate barrier)
        float4 p2n[3], g2n[3], en[3];
        if (more) {
            const float* p3 = pb + (size_t)(t + 2) * fs;
            const float* g3 = gb + (size_t)(t + 2) * fs;
            p2n[0] = ld4(p3 + coff);
            p2n[1] = ld4(p3 + coff + FRAME_PIX);
            p2n[2] = ld4(p3 + coff + 2 * FRAME_PIX);
            g2n[0] = ld4(g3 + coff);
            g2n[1] = ld4(g3 + coff + FRAME_PIX);
            g2n[2] = ld4(g3 + coff + 2 * FRAME_PIX);
            const float* eb = e_img ? g3 : p3;
            en[0] = make_float4(0.f,0.f,0.f,0.f); en[1] = en[0]; en[2] = en[0];
            if (e_act && e_val) {
                en[0] = ld4(eb + e_off);
                en[1] = ld4(eb + e_off + FRAME_PIX);
                en[2] = ld4(eb + e_off + 2 * FRAME_PIX);
            }
        }

        // Pair-t compute: Sobel on gray(t) in LDS, It vs gray(t+1) in regs
        const float4 gp2 = gray4(p2c[0], p2c[1], p2c[2]);
        const float4 gg2 = gray4(g2c[0], g2c[1], g2c[2]);

        float up[4], vp[4];
        #pragma unroll
        for (int img = 0; img < 2; ++img) {
            // padded floats cx+3..cx+8 -> aligned float4s at cx, cx+4, cx+8
            float w0[6], w1[6], w2[6];
            {
                const float* p = &gbuf[img][r][cx];
                const float4 A = ld4(p), B = ld4(p + 4), C = ld4(p + 8);
                w0[0] = A.w; w0[1] = B.x; w0[2] = B.y; w0[3] = B.z; w0[4] = B.w; w0[5] = C.x;
            }
            {
                const float* p = &gbuf[img][r + 1][cx];
                const float4 A = ld4(p), B = ld4(p + 4), C = ld4(p + 8);
                w1[0] = A.w; w1[1] = B.x; w1[2] = B.y; w1[3] = B.z; w1[4] = B.w; w1[5] = C.x;
            }
            {
                const float* p = &gbuf[img][r + 2][cx];
                const float4 A = ld4(p), B = ld4(p + 4), C = ld4(p + 8);
                w2[0] = A.w; w2[1] = B.x; w2[2] = B.y; w2[3] = B.z; w2[4] = B.w; w2[5] = C.x;
            }
            const float4 gr2 = img ? gg2 : gp2;
            const float g2a[4] = {gr2.x, gr2.y, gr2.z, gr2.w};
            #pragma unroll
            for (int j = 0; j < 4; ++j) {
                const float Ix = (w0[j] - w0[j + 2]) + 2.0f * (w1[j] - w1[j + 2]) + (w2[j] - w2[j + 2]);
                const float Iy = (w0[j] + 2.0f * w0[j + 1] + w0[j + 2])
                               - (w2[j] + 2.0f * w2[j + 1] + w2[j + 2]);
                const float It = g2a[j] - w1[j + 1];
                const float inv = 1.0f / (Ix * Ix + Iy * Iy + EPS);
                if (img == 0) {
                    up[j] = -(Ix * It) * inv;
                    vp[j] = -(Iy * It) * inv;
                } else {
                    s += (fabsf(up[j] + (Ix * It) * inv) + fabsf(vp[j] + (Iy * It) * inv)) * mmc[j];
                }
            }
        }

        if (more) {
            // mm for pair t+1 (uses g2c before it is overwritten)
            float mmn[4];
            mmn[0] = (fabsf(g2n[0].x - g2c[0].x) + fabsf(g2n[1].x - g2c[1].x) + fabsf(g2n[2].x - g2c[2].x)) * (1.f/3.f);
            mmn[1] = (fabsf(g2n[0].y - g2c[0].y) + fabsf(g2n[1].y - g2c[1].y) + fabsf(g2n[2].y - g2c[2].y)) * (1.f/3.f);
            mmn[2] = (fabsf(g2n[0].z - g2c[0].z) + fabsf(g2n[1].z - g2c[1].z) + fabsf(g2n[2].z - g2c[2].z)) * (1.f/3.f);
            mmn[3] = (fabsf(g2n[0].w - g2c[0].w) + fabsf(g2n[1].w - g2c[1].w) + fabsf(g2n[2].w - g2c[2].w)) * (1.f/3.f);

            __syncthreads();
            // Rotate: gray(t+1) into LDS (center from regs, extras from ecur)
            st4(&gbuf[0][r + 1][4 + cx], gp2);
            st4(&gbuf[1][r + 1][4 + cx], gg2);
            if (e_act) st4(e_dst, gray4(ecur[0], ecur[1], ecur[2]));
            #pragma unroll
            for (int k = 0; k < 3; ++k) {
                p2c[k] = p2n[k];
                g2c[k] = g2n[k];
                ecur[k] = en[k];
            }
            mmc[0] = mmn[0]; mmc[1] = mmn[1]; mmc[2] = mmn[2]; mmc[3] = mmn[3];
            __syncthreads();
        }
    }

    // ---- Block reduction -> one partial per block ----
    #pragma unroll
    for (int off = 32; off > 0; off >>= 1) s += __shfl_down(s, off, 64);

    __shared__ float wsum[4];
    if ((tid & 63) == 0) wsum[tid >> 6] = s;
    __syncthreads();
    if (tid == 0) {
        partial[(b * 2 + half) * (NYT * NXT) + blockIdx.x] =
            wsum[0] + wsum[1] + wsum[2] + wsum[3];
    }
}

__global__ __launch_bounds__(256) void reduce_kernel(
    const float* __restrict__ partial, float* __restrict__ out)
{
    const float4 v = ld4(partial + threadIdx.x * 4);   // 1024 floats total
    float s = (v.x + v.y) + (v.z + v.w);
    #pragma unroll
    for (int off = 32; off > 0; off >>= 1) s += __shfl_down(s, off, 64);

    __shared__ float wsum[4];
    if ((threadIdx.x & 63) == 0) wsum[threadIdx.x >> 6] = s;
    __syncthreads();
    if (threadIdx.x == 0) {
        out[0] = (wsum[0] + wsum[1] + wsum[2] + wsum[3]) * INV_N;
    }
}

extern "C" void kernel_launch(void* const* d_in, const int* in_sizes, int n_in,
                              void* d_out, int out_size, void* d_ws, size_t ws_size,
                              hipStream_t stream) {
    const float* pred = (const float*)d_in[0];
    const float* gt   = (const float*)d_in[1];
    float* partial    = (float*)d_ws;     // NBLK floats = 4096 B
    float* out        = (float*)d_out;

    dim3 grid(NYT * NXT, 2, BB);          // (64, 2, 8) = 1024 blocks
    dim3 block(256);
    flow_loss_kernel<<<grid, block, 0, stream>>>(pred, gt, partial);
    reduce_kernel<<<1, 256, 0, stream>>>(partial, out);
}